// Round 5
// baseline (196.402 us; speedup 1.0000x reference)
//
#include <hip/hip_runtime.h>

typedef unsigned long long u64;

// Problem constants (fixed by reference file)
#define N_TRUCK 100000
#define BLK 256
#define NB 128           // buckets per graph
#define NPB 782          // nodes per bucket: ceil(100000/128)
#define CAP 16384        // slots per bucket (mean 12500, sigma ~111 -> 35 sigma slack)
#define PB 256           // placer chunks
#define BLK_P 1024       // threads per place/deg/agg block
#define CHUNK_MAX 6272   // >= ceil(E/PB)=6250
#define ROW_MASK 0x1FFFFu
#define LC_SHIFT 17

// ---------------- ws layout (bytes), new path ----------------
// curT i32[128] @ 0 (512) | curC i32[128] @ 512 (512) | G f32[36] @ 1024
// dis_t @ 4096 (400000) | dis_c @ 404096 | s_t @ 804096 | y4 @ 1204096 (1600000)
// pT  u32[128*CAP] @ 2804096  (8388608)
// pC8 u64[128*CAP] @ 11192704 (16777216)  ends 27969920
#define WS_NEED_NEW 27969920ULL

// ============ fused place (+G on last block) ============

__global__ void k_place(const int* __restrict__ trow, const int* __restrict__ tcol,
                        const int* __restrict__ crow, const int* __restrict__ ccol,
                        const float* __restrict__ ew, int E_,
                        int* __restrict__ curT, int* __restrict__ curC,
                        unsigned* __restrict__ pT, u64* __restrict__ pC8,
                        const float* __restrict__ Wt, const float* __restrict__ bt,
                        const float* __restrict__ Wc, const float* __restrict__ bc,
                        const float* __restrict__ wlin, float* __restrict__ G) {
    if (blockIdx.x == PB) {
        // fused k_G: G[a][b] = sum_h M[a,h]*M[b,h]*wlin[h]
        int l = threadIdx.x;
        if (l < 64) {
            float acc[21];
#pragma unroll
            for (int k = 0; k < 21; k++) acc[k] = 0.0f;
            for (int h = l; h < 128; h += 64) {
                float m[6] = {Wt[h], bt[h], Wc[h], Wc[128 + h], Wc[256 + h], bc[h]};
                float w = wlin[h];
                int k = 0;
#pragma unroll
                for (int a = 0; a < 6; a++)
#pragma unroll
                    for (int b2 = a; b2 < 6; b2++)
                        acc[k++] += m[a] * m[b2] * w;
            }
            int k = 0;
#pragma unroll
            for (int a = 0; a < 6; a++)
#pragma unroll
                for (int b2 = a; b2 < 6; b2++) {
                    float v = acc[k++];
#pragma unroll
                    for (int off = 32; off; off >>= 1) v += __shfl_down(v, off);
                    if (l == 0) {
                        G[a * 6 + b2] = v;
                        G[b2 * 6 + a] = v;
                    }
                }
        }
        return;
    }

    __shared__ u64 pay8[CHUNK_MAX];          // car payload; truck reuses as u32[]
    __shared__ unsigned char bkt[CHUNK_MAX];
    __shared__ int hist[NB];                 // hist -> local cursor
    __shared__ int shiftA[NB];               // scan temp -> flush shift
    unsigned* pay4 = (unsigned*)pay8;

    int b = blockIdx.x;
    int chunk = (E_ + PB - 1) / PB;
    int s0 = b * chunk, s1 = min(E_, s0 + chunk);
    int n = s1 - s0;
    int t = threadIdx.x;

    // ================= truck graph =================
    for (int k = t; k < NB; k += BLK_P) hist[k] = 0;
    __syncthreads();
    for (int j = s0 + t; j < s1; j += BLK_P) atomicAdd(&hist[tcol[j] / NPB], 1);
    __syncthreads();
    int myCnt = (t < NB) ? hist[t] : 0;
    if (t < NB) shiftA[t] = myCnt;
    __syncthreads();
    for (int off = 1; off < NB; off <<= 1) {
        int x = (t < NB && t >= off) ? shiftA[t - off] : 0;
        __syncthreads();
        if (t < NB) shiftA[t] += x;
        __syncthreads();
    }
    if (t < NB) {
        int excl = shiftA[t] - myCnt;                     // local exclusive base
        int gstart = t * CAP + atomicAdd(&curT[t], myCnt); // global run start
        shiftA[t] = gstart - excl;
        hist[t] = excl;                                   // local cursor
    }
    __syncthreads();
    for (int j = s0 + t; j < s1; j += BLK_P) {
        int tc = tcol[j];
        int k = tc / NPB;
        int s = atomicAdd(&hist[k], 1);
        pay4[s] = ((unsigned)(tc - k * NPB) << LC_SHIFT) | (unsigned)trow[j];
        bkt[s] = (unsigned char)k;
    }
    __syncthreads();
    for (int s = t; s < n; s += BLK_P)
        pT[s + shiftA[bkt[s]]] = pay4[s];
    __syncthreads();

    // ================= car graph =================
    for (int k = t; k < NB; k += BLK_P) hist[k] = 0;
    __syncthreads();
    for (int j = s0 + t; j < s1; j += BLK_P) atomicAdd(&hist[ccol[j] / NPB], 1);
    __syncthreads();
    myCnt = (t < NB) ? hist[t] : 0;
    if (t < NB) shiftA[t] = myCnt;
    __syncthreads();
    for (int off = 1; off < NB; off <<= 1) {
        int x = (t < NB && t >= off) ? shiftA[t - off] : 0;
        __syncthreads();
        if (t < NB) shiftA[t] += x;
        __syncthreads();
    }
    if (t < NB) {
        int excl = shiftA[t] - myCnt;
        int gstart = t * CAP + atomicAdd(&curC[t], myCnt);
        shiftA[t] = gstart - excl;
        hist[t] = excl;
    }
    __syncthreads();
    for (int j = s0 + t; j < s1; j += BLK_P) {
        int cc = ccol[j];
        int k = cc / NPB;
        int s = atomicAdd(&hist[k], 1);
        unsigned lo = ((unsigned)(cc - k * NPB) << LC_SHIFT) | (unsigned)crow[j];
        pay8[s] = ((u64)__float_as_uint(ew[j]) << 32) | lo;
        bkt[s] = (unsigned char)k;
    }
    __syncthreads();
    for (int s = t; s < n; s += BLK_P)
        pC8[s + shiftA[bkt[s]]] = pay8[s];
}

// ============ per-bucket degree -> dis (2*NB blocks) ============

__global__ void k_deg2(const unsigned* __restrict__ pT, const u64* __restrict__ pC8,
                       const int* __restrict__ curT, const int* __restrict__ curC,
                       float* __restrict__ dis_t, float* __restrict__ dis_c,
                       int nt, int nc) {
    __shared__ float acc[NPB];
    int b = blockIdx.x;
    bool car = b >= NB;
    int bk = car ? b - NB : b;
    int cnt = car ? curC[bk] : curT[bk];
    int s0 = bk * CAP;
    for (int k = threadIdx.x; k < NPB; k += blockDim.x) acc[k] = 0.0f;
    __syncthreads();
    if (car) {
        for (int j = threadIdx.x; j < cnt; j += blockDim.x) {
            u64 v = pC8[s0 + j];
            atomicAdd(&acc[((unsigned)v) >> LC_SHIFT], __uint_as_float((unsigned)(v >> 32)));
        }
    } else {
        for (int j = threadIdx.x; j < cnt; j += blockDim.x)
            atomicAdd(&acc[pT[s0 + j] >> LC_SHIFT], 1.0f);
    }
    __syncthreads();
    float* dis = car ? dis_c : dis_t;
    int ntot = car ? nc : nt;
    for (int nn = threadIdx.x; nn < NPB; nn += blockDim.x) {
        int node = bk * NPB + nn;
        if (node < ntot) dis[node] = rsqrtf(acc[nn] + 1.0f);
    }
}

// ============ per-bucket aggregation -> s_t / y4 (2*NB blocks) ============

__global__ void k_agg(const unsigned* __restrict__ pT, const u64* __restrict__ pC8,
                      const int* __restrict__ curT, const int* __restrict__ curC,
                      const float* __restrict__ dis_t, const float* __restrict__ dis_c,
                      const float* __restrict__ x_car,
                      float* __restrict__ s_t, float4* __restrict__ y4,
                      int nt, int nc) {
    int b = blockIdx.x;
    if (b < NB) {
        __shared__ float sacc[NPB];
        int cnt = curT[b];
        int s0 = b * CAP;
        for (int k = threadIdx.x; k < NPB; k += blockDim.x) sacc[k] = 0.0f;
        __syncthreads();
        for (int j = threadIdx.x; j < cnt; j += blockDim.x) {
            unsigned v = pT[s0 + j];
            atomicAdd(&sacc[v >> LC_SHIFT], dis_t[v & ROW_MASK]);
        }
        __syncthreads();
        for (int nn = threadIdx.x; nn < NPB; nn += blockDim.x) {
            int node = b * NPB + nn;
            if (node < nt) {
                float d = dis_t[node];
                s_t[node] = fmaf(d, sacc[nn], d * d);
            }
        }
    } else {
        int bk = b - NB;
        __shared__ float y[NPB * 5];   // stride 5: avoid stride-4 bank aliasing
        __shared__ float dcl[NPB];
        int cnt = curC[bk];
        int s0 = bk * CAP;
        for (int k = threadIdx.x; k < NPB * 5; k += blockDim.x) y[k] = 0.0f;
        for (int k = threadIdx.x; k < NPB; k += blockDim.x) {
            int node = bk * NPB + k;
            dcl[k] = (node < nc) ? dis_c[node] : 0.0f;
        }
        __syncthreads();
        for (int j = threadIdx.x; j < cnt; j += blockDim.x) {
            u64 v = pC8[s0 + j];
            int r = (int)((unsigned)v & ROW_MASK);
            int lc = (int)(((unsigned)v) >> LC_SHIFT);
            float nrm = dis_c[r] * __uint_as_float((unsigned)(v >> 32)) * dcl[lc];
            const float* xr = &x_car[3 * r];
            atomicAdd(&y[lc * 5 + 0], nrm * xr[0]);
            atomicAdd(&y[lc * 5 + 1], nrm * xr[1]);
            atomicAdd(&y[lc * 5 + 2], nrm * xr[2]);
        }
        __syncthreads();
        for (int nn = threadIdx.x; nn < NPB; nn += blockDim.x) {
            int node = bk * NPB + nn;
            if (node < nc) {
                float d2 = dcl[nn] * dcl[nn];
                const float* xn = &x_car[3 * node];
                y4[node] = make_float4(fmaf(d2, xn[0], y[nn * 5 + 0]),
                                       fmaf(d2, xn[1], y[nn * 5 + 1]),
                                       fmaf(d2, xn[2], y[nn * 5 + 2]), 1.0f);
            }
        }
    }
}

// ============ pair scorer ============

__device__ __forceinline__ void load_z(int i, const float* __restrict__ s_t,
                                       const float4* __restrict__ y4, float z[6]) {
    if (i < N_TRUCK) {
        z[0] = s_t[i]; z[1] = 1.0f; z[2] = 0.0f; z[3] = 0.0f; z[4] = 0.0f; z[5] = 0.0f;
    } else {
        float4 y = y4[i - N_TRUCK];
        z[0] = 0.0f; z[1] = 0.0f; z[2] = y.x; z[3] = y.y; z[4] = y.z; z[5] = 1.0f;
    }
}

__global__ void k_pairs(const int* __restrict__ src, const int* __restrict__ dst, int P_,
                        const float* __restrict__ s_t, const float4* __restrict__ y4,
                        const float* __restrict__ G, const float* __restrict__ b_lin,
                        float* __restrict__ out) {
    int p = blockIdx.x * blockDim.x + threadIdx.x;
    if (p >= P_) return;
    float zs[6], zd[6];
    load_z(src[p], s_t, y4, zs);
    load_z(dst[p], s_t, y4, zd);
    float acc = 0.0f;
#pragma unroll
    for (int a = 0; a < 6; a++) {
        float g = 0.0f;
#pragma unroll
        for (int b = 0; b < 6; b++) g = fmaf(G[a * 6 + b], zd[b], g);
        acc = fmaf(zs[a], g, acc);
    }
    out[p] = acc + b_lin[0];
}

// ============ fallback (round-1 proven global-atomic path) ============

__global__ void k_G(const float* __restrict__ Wt, const float* __restrict__ bt,
                    const float* __restrict__ Wc, const float* __restrict__ bc,
                    const float* __restrict__ wlin, float* __restrict__ G) {
    int l = threadIdx.x;
    float acc[21];
#pragma unroll
    for (int k = 0; k < 21; k++) acc[k] = 0.0f;
    for (int h = l; h < 128; h += 64) {
        float m[6] = {Wt[h], bt[h], Wc[h], Wc[128 + h], Wc[256 + h], bc[h]};
        float w = wlin[h];
        int k = 0;
#pragma unroll
        for (int a = 0; a < 6; a++)
#pragma unroll
            for (int b = a; b < 6; b++)
                acc[k++] += m[a] * m[b] * w;
    }
    int k = 0;
#pragma unroll
    for (int a = 0; a < 6; a++)
#pragma unroll
        for (int b = a; b < 6; b++) {
            float v = acc[k++];
#pragma unroll
            for (int off = 32; off; off >>= 1) v += __shfl_down(v, off);
            if (l == 0) {
                G[a * 6 + b] = v;
                G[b * 6 + a] = v;
            }
        }
}

__global__ void k_deg(const int* __restrict__ tcol, const int* __restrict__ ccol,
                      const float* __restrict__ ew, int E_,
                      int* __restrict__ cnt_t, float* __restrict__ degw_c) {
    int i = blockIdx.x * blockDim.x + threadIdx.x;
    if (i >= E_) return;
    atomicAdd(&cnt_t[tcol[i]], 1);
    atomicAdd(&degw_c[ccol[i]], ew[i]);
}

__global__ void k_dis(const int* __restrict__ cnt_t, const float* __restrict__ degw_c,
                      float* __restrict__ dis_t, float* __restrict__ dis_c,
                      int nt, int nc) {
    int i = blockIdx.x * blockDim.x + threadIdx.x;
    if (i < nt) dis_t[i] = rsqrtf((float)cnt_t[i] + 1.0f);
    if (i < nc) dis_c[i] = rsqrtf(degw_c[i] + 1.0f);
}

__global__ void k_scat(const int* __restrict__ trow, const int* __restrict__ tcol,
                       const int* __restrict__ crow, const int* __restrict__ ccol,
                       const float* __restrict__ ew, int E_,
                       const float* __restrict__ dis_t, const float* __restrict__ dis_c,
                       const float* __restrict__ x_car,
                       float* __restrict__ sumdis, float* __restrict__ y4) {
    int i = blockIdx.x * blockDim.x + threadIdx.x;
    if (i >= E_) return;
    atomicAdd(&sumdis[tcol[i]], dis_t[trow[i]]);
    int r = crow[i], c = ccol[i];
    float nrm = dis_c[r] * ew[i] * dis_c[c];
    atomicAdd(&y4[c * 4 + 0], nrm * x_car[r * 3 + 0]);
    atomicAdd(&y4[c * 4 + 1], nrm * x_car[r * 3 + 1]);
    atomicAdd(&y4[c * 4 + 2], nrm * x_car[r * 3 + 2]);
}

__global__ void k_fin(int nt, int nc,
                      const float* __restrict__ dis_t, const float* __restrict__ sumdis,
                      float* __restrict__ s_t,
                      const float* __restrict__ dis_c, const float* __restrict__ x_car,
                      float* __restrict__ y4) {
    int i = blockIdx.x * blockDim.x + threadIdx.x;
    if (i < nt) {
        float d = dis_t[i];
        s_t[i] = d * sumdis[i] + d * d;
    }
    if (i < nc) {
        float d2 = dis_c[i] * dis_c[i];
        y4[i * 4 + 0] += d2 * x_car[i * 3 + 0];
        y4[i * 4 + 1] += d2 * x_car[i * 3 + 1];
        y4[i * 4 + 2] += d2 * x_car[i * 3 + 2];
        y4[i * 4 + 3] = 1.0f;
    }
}

// ============ launch ============

extern "C" void kernel_launch(void* const* d_in, const int* in_sizes, int n_in,
                              void* d_out, int out_size, void* d_ws, size_t ws_size,
                              hipStream_t stream) {
    const float* x_car  = (const float*)d_in[0];
    const int*   ei_t   = (const int*)d_in[1];
    const int*   ei_c   = (const int*)d_in[2];
    const float* ew_c   = (const float*)d_in[3];
    const int*   src    = (const int*)d_in[4];
    const int*   dst    = (const int*)d_in[5];
    const float* W_t    = (const float*)d_in[7];
    const float* b_t    = (const float*)d_in[8];
    const float* W_c    = (const float*)d_in[9];
    const float* b_c    = (const float*)d_in[10];
    const float* W_lin  = (const float*)d_in[11];
    const float* b_lin  = (const float*)d_in[12];
    float* out = (float*)d_out;

    const int NC = in_sizes[0] / 3;   // 100000
    const int E_ = in_sizes[1] / 2;   // 1600000
    const int P_ = in_sizes[4];       // 200000

    const int* trow = ei_t;  const int* tcol = ei_t + E_;
    const int* crow = ei_c;  const int* ccol = ei_c + E_;

    char* ws = (char*)d_ws;
    int gP = (P_ + BLK - 1) / BLK;
    int chunk = (E_ + PB - 1) / PB;

    if (ws_size >= WS_NEED_NEW && chunk <= CHUNK_MAX && NB * NPB >= N_TRUCK &&
        NB * NPB >= NC && NB * CAP >= E_ + 16384) {
        int*      curT  = (int*)(ws + 0);
        int*      curC  = (int*)(ws + 512);
        float*    G     = (float*)(ws + 1024);
        float*    dis_t = (float*)(ws + 4096);
        float*    dis_c = (float*)(ws + 404096);
        float*    s_t   = (float*)(ws + 804096);
        float*    y4    = (float*)(ws + 1204096);
        unsigned* pT    = (unsigned*)(ws + 2804096);
        u64*      pC8   = (u64*)(ws + 11192704);

        hipMemsetAsync(ws, 0, 1024, stream);   // cursors
        k_place<<<PB + 1, BLK_P, 0, stream>>>(trow, tcol, crow, ccol, ew_c, E_,
                                              curT, curC, pT, pC8,
                                              W_t, b_t, W_c, b_c, W_lin, G);
        k_deg2<<<2 * NB, BLK_P, 0, stream>>>(pT, pC8, curT, curC, dis_t, dis_c,
                                             N_TRUCK, NC);
        k_agg<<<2 * NB, BLK_P, 0, stream>>>(pT, pC8, curT, curC, dis_t, dis_c,
                                            x_car, s_t, (float4*)y4, N_TRUCK, NC);
        k_pairs<<<gP, BLK, 0, stream>>>(src, dst, P_, s_t, (const float4*)y4, G, b_lin, out);
    } else {
        // fallback: round-1 proven global-atomic path (~4 MB ws)
        int*   cnt_t  = (int*)(ws + 0);
        float* sumdis = (float*)(ws + 400000);
        float* degw_c = (float*)(ws + 800000);
        float* y4    = (float*)(ws + 1200000);
        float* dis_t  = (float*)(ws + 2800000);
        float* dis_c  = (float*)(ws + 3200000);
        float* s_t    = (float*)(ws + 3600000);
        float* G      = (float*)(ws + 4000000);

        hipMemsetAsync(ws, 0, 2800000, stream);
        int gE = (E_ + BLK - 1) / BLK;
        int gN = ((N_TRUCK > NC ? N_TRUCK : NC) + BLK - 1) / BLK;
        k_deg<<<gE, BLK, 0, stream>>>(tcol, ccol, ew_c, E_, cnt_t, degw_c);
        k_dis<<<gN, BLK, 0, stream>>>(cnt_t, degw_c, dis_t, dis_c, N_TRUCK, NC);
        k_scat<<<gE, BLK, 0, stream>>>(trow, tcol, crow, ccol, ew_c, E_,
                                       dis_t, dis_c, x_car, sumdis, y4);
        k_fin<<<gN, BLK, 0, stream>>>(N_TRUCK, NC, dis_t, sumdis, s_t, dis_c, x_car, y4);
        k_G<<<1, 64, 0, stream>>>(W_t, b_t, W_c, b_c, W_lin, G);
        k_pairs<<<gP, BLK, 0, stream>>>(src, dst, P_, s_t, (const float4*)y4, G, b_lin, out);
    }
}

// Round 6
// 184.182 us; speedup vs baseline: 1.0663x; 1.0663x over previous
//
#include <hip/hip_runtime.h>

typedef unsigned long long u64;

// Problem constants (fixed by reference file)
#define N_TRUCK 100000
#define BLK 256
#define NB 256           // buckets per graph
#define NPB 391          // nodes per bucket: ceil(100000/256)
#define CAP 8192         // slots per bucket (mean 6250, sigma ~79 -> 24 sigma slack)
#define PB 512           // placer chunks
#define BLK_P 1024       // threads per place/deg/agg block
#define CHUNK_MAX 3136   // >= ceil(E/PB)=3125
#define ROW_MASK 0x1FFFFu
#define LC_SHIFT 17

// ---------------- ws layout (bytes), new path ----------------
// curT i32[256] @ 0 (1024) | curC i32[256] @ 1024 (1024) | G f32[36] @ 2048
// dis_t @ 4096 | dis_c @ 404096 | s_t @ 804096 | y4 @ 1204096 (1600000)
// xs4 f32x4[100000] @ 2804096 (1600000)
// pT  u32[256*CAP] @ 4404096  (8388608)
// pC8 u64[256*CAP] @ 12792704 (16777216)  ends 29569920
#define WS_NEED_NEW 29569920ULL

// ============ fused place (+G on last block) ============

__global__ void k_place(const int* __restrict__ trow, const int* __restrict__ tcol,
                        const int* __restrict__ crow, const int* __restrict__ ccol,
                        const float* __restrict__ ew, int E_,
                        int* __restrict__ curT, int* __restrict__ curC,
                        unsigned* __restrict__ pT, u64* __restrict__ pC8,
                        const float* __restrict__ Wt, const float* __restrict__ bt,
                        const float* __restrict__ Wc, const float* __restrict__ bc,
                        const float* __restrict__ wlin, float* __restrict__ G) {
    if (blockIdx.x == PB) {
        // fused k_G: G[a][b] = sum_h M[a,h]*M[b,h]*wlin[h]
        int l = threadIdx.x;
        if (l < 64) {
            float acc[21];
#pragma unroll
            for (int k = 0; k < 21; k++) acc[k] = 0.0f;
            for (int h = l; h < 128; h += 64) {
                float m[6] = {Wt[h], bt[h], Wc[h], Wc[128 + h], Wc[256 + h], bc[h]};
                float w = wlin[h];
                int k = 0;
#pragma unroll
                for (int a = 0; a < 6; a++)
#pragma unroll
                    for (int b2 = a; b2 < 6; b2++)
                        acc[k++] += m[a] * m[b2] * w;
            }
            int k = 0;
#pragma unroll
            for (int a = 0; a < 6; a++)
#pragma unroll
                for (int b2 = a; b2 < 6; b2++) {
                    float v = acc[k++];
#pragma unroll
                    for (int off = 32; off; off >>= 1) v += __shfl_down(v, off);
                    if (l == 0) {
                        G[a * 6 + b2] = v;
                        G[b2 * 6 + a] = v;
                    }
                }
        }
        return;
    }

    __shared__ u64 pay8[CHUNK_MAX];          // car payload; truck reuses as u32[]
    __shared__ unsigned char bkt[CHUNK_MAX];
    __shared__ int hist[NB];                 // hist -> local cursor
    __shared__ int shiftA[NB];               // scan temp -> flush shift
    unsigned* pay4 = (unsigned*)pay8;

    int b = blockIdx.x;
    int chunk = (E_ + PB - 1) / PB;
    int s0 = b * chunk, s1 = min(E_, s0 + chunk);
    int n = s1 - s0;
    int t = threadIdx.x;

    // ================= truck graph =================
    for (int k = t; k < NB; k += BLK_P) hist[k] = 0;
    __syncthreads();
    for (int j = s0 + t; j < s1; j += BLK_P) atomicAdd(&hist[tcol[j] / NPB], 1);
    __syncthreads();
    int myCnt = (t < NB) ? hist[t] : 0;
    if (t < NB) shiftA[t] = myCnt;
    __syncthreads();
    for (int off = 1; off < NB; off <<= 1) {
        int x = (t < NB && t >= off) ? shiftA[t - off] : 0;
        __syncthreads();
        if (t < NB) shiftA[t] += x;
        __syncthreads();
    }
    if (t < NB) {
        int excl = shiftA[t] - myCnt;                      // local exclusive base
        int gstart = t * CAP + atomicAdd(&curT[t], myCnt); // global run start
        shiftA[t] = gstart - excl;
        hist[t] = excl;                                    // local cursor
    }
    __syncthreads();
    for (int j = s0 + t; j < s1; j += BLK_P) {
        int tc = tcol[j];
        int k = tc / NPB;
        int s = atomicAdd(&hist[k], 1);
        pay4[s] = ((unsigned)(tc - k * NPB) << LC_SHIFT) | (unsigned)trow[j];
        bkt[s] = (unsigned char)k;
    }
    __syncthreads();
    for (int s = t; s < n; s += BLK_P)
        pT[s + shiftA[bkt[s]]] = pay4[s];
    __syncthreads();

    // ================= car graph =================
    for (int k = t; k < NB; k += BLK_P) hist[k] = 0;
    __syncthreads();
    for (int j = s0 + t; j < s1; j += BLK_P) atomicAdd(&hist[ccol[j] / NPB], 1);
    __syncthreads();
    myCnt = (t < NB) ? hist[t] : 0;
    if (t < NB) shiftA[t] = myCnt;
    __syncthreads();
    for (int off = 1; off < NB; off <<= 1) {
        int x = (t < NB && t >= off) ? shiftA[t - off] : 0;
        __syncthreads();
        if (t < NB) shiftA[t] += x;
        __syncthreads();
    }
    if (t < NB) {
        int excl = shiftA[t] - myCnt;
        int gstart = t * CAP + atomicAdd(&curC[t], myCnt);
        shiftA[t] = gstart - excl;
        hist[t] = excl;
    }
    __syncthreads();
    for (int j = s0 + t; j < s1; j += BLK_P) {
        int cc = ccol[j];
        int k = cc / NPB;
        int s = atomicAdd(&hist[k], 1);
        unsigned lo = ((unsigned)(cc - k * NPB) << LC_SHIFT) | (unsigned)crow[j];
        pay8[s] = ((u64)__float_as_uint(ew[j]) << 32) | lo;
        bkt[s] = (unsigned char)k;
    }
    __syncthreads();
    for (int s = t; s < n; s += BLK_P)
        pC8[s + shiftA[bkt[s]]] = pay8[s];
}

// ============ per-bucket degree -> dis (+xs4 for car); 2*NB blocks ============

__global__ void k_deg2(const unsigned* __restrict__ pT, const u64* __restrict__ pC8,
                       const int* __restrict__ curT, const int* __restrict__ curC,
                       const float* __restrict__ x_car,
                       float* __restrict__ dis_t, float* __restrict__ dis_c,
                       float4* __restrict__ xs4, int nt, int nc) {
    __shared__ float acc[NPB];
    int b = blockIdx.x;
    bool car = b >= NB;
    int bk = car ? b - NB : b;
    int cnt = car ? curC[bk] : curT[bk];
    int s0 = bk * CAP;
    for (int k = threadIdx.x; k < NPB; k += blockDim.x) acc[k] = 0.0f;
    __syncthreads();
    if (car) {
        const ulonglong2* p2 = (const ulonglong2*)(pC8 + s0);
        int half = cnt >> 1;
        for (int j = threadIdx.x; j < half; j += blockDim.x) {
            ulonglong2 v = p2[j];
            atomicAdd(&acc[((unsigned)v.x) >> LC_SHIFT], __uint_as_float((unsigned)(v.x >> 32)));
            atomicAdd(&acc[((unsigned)v.y) >> LC_SHIFT], __uint_as_float((unsigned)(v.y >> 32)));
        }
        if ((cnt & 1) && threadIdx.x == 0) {
            u64 v = pC8[s0 + cnt - 1];
            atomicAdd(&acc[((unsigned)v) >> LC_SHIFT], __uint_as_float((unsigned)(v >> 32)));
        }
    } else {
        const uint2* p2 = (const uint2*)(pT + s0);
        int half = cnt >> 1;
        for (int j = threadIdx.x; j < half; j += blockDim.x) {
            uint2 v = p2[j];
            atomicAdd(&acc[v.x >> LC_SHIFT], 1.0f);
            atomicAdd(&acc[v.y >> LC_SHIFT], 1.0f);
        }
        if ((cnt & 1) && threadIdx.x == 0)
            atomicAdd(&acc[pT[s0 + cnt - 1] >> LC_SHIFT], 1.0f);
    }
    __syncthreads();
    int ntot = car ? nc : nt;
    for (int nn = threadIdx.x; nn < NPB; nn += blockDim.x) {
        int node = bk * NPB + nn;
        if (node < ntot) {
            float d = rsqrtf(acc[nn] + 1.0f);
            if (car) {
                dis_c[node] = d;
                const float* xn = &x_car[3 * node];
                xs4[node] = make_float4(d * xn[0], d * xn[1], d * xn[2], d);
            } else {
                dis_t[node] = d;
            }
        }
    }
}

// ============ per-bucket aggregation -> s_t / y4 (2*NB blocks) ============

__global__ void k_agg(const unsigned* __restrict__ pT, const u64* __restrict__ pC8,
                      const int* __restrict__ curT, const int* __restrict__ curC,
                      const float* __restrict__ dis_t, const float* __restrict__ dis_c,
                      const float4* __restrict__ xs4,
                      float* __restrict__ s_t, float4* __restrict__ y4,
                      int nt, int nc) {
    int b = blockIdx.x;
    if (b < NB) {
        __shared__ float sacc[NPB];
        int cnt = curT[b];
        int s0 = b * CAP;
        for (int k = threadIdx.x; k < NPB; k += blockDim.x) sacc[k] = 0.0f;
        __syncthreads();
        const uint2* p2 = (const uint2*)(pT + s0);
        int half = cnt >> 1;
        for (int j = threadIdx.x; j < half; j += blockDim.x) {
            uint2 v = p2[j];
            float da = dis_t[v.x & ROW_MASK];
            float db = dis_t[v.y & ROW_MASK];
            atomicAdd(&sacc[v.x >> LC_SHIFT], da);
            atomicAdd(&sacc[v.y >> LC_SHIFT], db);
        }
        if ((cnt & 1) && threadIdx.x == 0) {
            unsigned v = pT[s0 + cnt - 1];
            atomicAdd(&sacc[v >> LC_SHIFT], dis_t[v & ROW_MASK]);
        }
        __syncthreads();
        for (int nn = threadIdx.x; nn < NPB; nn += blockDim.x) {
            int node = b * NPB + nn;
            if (node < nt) {
                float d = dis_t[node];
                s_t[node] = fmaf(d, sacc[nn], d * d);
            }
        }
    } else {
        int bk = b - NB;
        __shared__ float y[NPB * 5];   // stride 5: avoid stride-4 bank aliasing
        __shared__ float dcl[NPB];
        int cnt = curC[bk];
        int s0 = bk * CAP;
        for (int k = threadIdx.x; k < NPB * 5; k += blockDim.x) y[k] = 0.0f;
        for (int k = threadIdx.x; k < NPB; k += blockDim.x) {
            int node = bk * NPB + k;
            dcl[k] = (node < nc) ? dis_c[node] : 0.0f;
        }
        __syncthreads();
        const ulonglong2* p2 = (const ulonglong2*)(pC8 + s0);
        int half = cnt >> 1;
        for (int j = threadIdx.x; j < half; j += blockDim.x) {
            ulonglong2 v = p2[j];
            unsigned loa = (unsigned)v.x, lob = (unsigned)v.y;
            float4 xa = xs4[loa & ROW_MASK];     // dis_c[r] pre-folded
            float4 xb = xs4[lob & ROW_MASK];
            int lca = loa >> LC_SHIFT, lcb = lob >> LC_SHIFT;
            float na = __uint_as_float((unsigned)(v.x >> 32)) * dcl[lca];
            float nb = __uint_as_float((unsigned)(v.y >> 32)) * dcl[lcb];
            atomicAdd(&y[lca * 5 + 0], na * xa.x);
            atomicAdd(&y[lca * 5 + 1], na * xa.y);
            atomicAdd(&y[lca * 5 + 2], na * xa.z);
            atomicAdd(&y[lcb * 5 + 0], nb * xb.x);
            atomicAdd(&y[lcb * 5 + 1], nb * xb.y);
            atomicAdd(&y[lcb * 5 + 2], nb * xb.z);
        }
        if ((cnt & 1) && threadIdx.x == 0) {
            u64 v = pC8[s0 + cnt - 1];
            unsigned lo = (unsigned)v;
            float4 xa = xs4[lo & ROW_MASK];
            int lc = lo >> LC_SHIFT;
            float na = __uint_as_float((unsigned)(v >> 32)) * dcl[lc];
            atomicAdd(&y[lc * 5 + 0], na * xa.x);
            atomicAdd(&y[lc * 5 + 1], na * xa.y);
            atomicAdd(&y[lc * 5 + 2], na * xa.z);
        }
        __syncthreads();
        for (int nn = threadIdx.x; nn < NPB; nn += blockDim.x) {
            int node = bk * NPB + nn;
            if (node < nc) {
                float d = dcl[nn];
                float4 xs = xs4[node];           // d*x already
                y4[node] = make_float4(fmaf(d, xs.x, y[nn * 5 + 0]),
                                       fmaf(d, xs.y, y[nn * 5 + 1]),
                                       fmaf(d, xs.z, y[nn * 5 + 2]), 1.0f);
            }
        }
    }
}

// ============ pair scorer ============

__device__ __forceinline__ void load_z(int i, const float* __restrict__ s_t,
                                       const float4* __restrict__ y4, float z[6]) {
    if (i < N_TRUCK) {
        z[0] = s_t[i]; z[1] = 1.0f; z[2] = 0.0f; z[3] = 0.0f; z[4] = 0.0f; z[5] = 0.0f;
    } else {
        float4 y = y4[i - N_TRUCK];
        z[0] = 0.0f; z[1] = 0.0f; z[2] = y.x; z[3] = y.y; z[4] = y.z; z[5] = 1.0f;
    }
}

__global__ void k_pairs(const int* __restrict__ src, const int* __restrict__ dst, int P_,
                        const float* __restrict__ s_t, const float4* __restrict__ y4,
                        const float* __restrict__ G, const float* __restrict__ b_lin,
                        float* __restrict__ out) {
    int p = blockIdx.x * blockDim.x + threadIdx.x;
    if (p >= P_) return;
    float zs[6], zd[6];
    load_z(src[p], s_t, y4, zs);
    load_z(dst[p], s_t, y4, zd);
    float acc = 0.0f;
#pragma unroll
    for (int a = 0; a < 6; a++) {
        float g = 0.0f;
#pragma unroll
        for (int b = 0; b < 6; b++) g = fmaf(G[a * 6 + b], zd[b], g);
        acc = fmaf(zs[a], g, acc);
    }
    out[p] = acc + b_lin[0];
}

// ============ fallback (round-1 proven global-atomic path) ============

__global__ void k_G(const float* __restrict__ Wt, const float* __restrict__ bt,
                    const float* __restrict__ Wc, const float* __restrict__ bc,
                    const float* __restrict__ wlin, float* __restrict__ G) {
    int l = threadIdx.x;
    float acc[21];
#pragma unroll
    for (int k = 0; k < 21; k++) acc[k] = 0.0f;
    for (int h = l; h < 128; h += 64) {
        float m[6] = {Wt[h], bt[h], Wc[h], Wc[128 + h], Wc[256 + h], bc[h]};
        float w = wlin[h];
        int k = 0;
#pragma unroll
        for (int a = 0; a < 6; a++)
#pragma unroll
            for (int b = a; b < 6; b++)
                acc[k++] += m[a] * m[b] * w;
    }
    int k = 0;
#pragma unroll
    for (int a = 0; a < 6; a++)
#pragma unroll
        for (int b = a; b < 6; b++) {
            float v = acc[k++];
#pragma unroll
            for (int off = 32; off; off >>= 1) v += __shfl_down(v, off);
            if (l == 0) {
                G[a * 6 + b] = v;
                G[b * 6 + a] = v;
            }
        }
}

__global__ void k_deg(const int* __restrict__ tcol, const int* __restrict__ ccol,
                      const float* __restrict__ ew, int E_,
                      int* __restrict__ cnt_t, float* __restrict__ degw_c) {
    int i = blockIdx.x * blockDim.x + threadIdx.x;
    if (i >= E_) return;
    atomicAdd(&cnt_t[tcol[i]], 1);
    atomicAdd(&degw_c[ccol[i]], ew[i]);
}

__global__ void k_dis(const int* __restrict__ cnt_t, const float* __restrict__ degw_c,
                      float* __restrict__ dis_t, float* __restrict__ dis_c,
                      int nt, int nc) {
    int i = blockIdx.x * blockDim.x + threadIdx.x;
    if (i < nt) dis_t[i] = rsqrtf((float)cnt_t[i] + 1.0f);
    if (i < nc) dis_c[i] = rsqrtf(degw_c[i] + 1.0f);
}

__global__ void k_scat(const int* __restrict__ trow, const int* __restrict__ tcol,
                       const int* __restrict__ crow, const int* __restrict__ ccol,
                       const float* __restrict__ ew, int E_,
                       const float* __restrict__ dis_t, const float* __restrict__ dis_c,
                       const float* __restrict__ x_car,
                       float* __restrict__ sumdis, float* __restrict__ y4) {
    int i = blockIdx.x * blockDim.x + threadIdx.x;
    if (i >= E_) return;
    atomicAdd(&sumdis[tcol[i]], dis_t[trow[i]]);
    int r = crow[i], c = ccol[i];
    float nrm = dis_c[r] * ew[i] * dis_c[c];
    atomicAdd(&y4[c * 4 + 0], nrm * x_car[r * 3 + 0]);
    atomicAdd(&y4[c * 4 + 1], nrm * x_car[r * 3 + 1]);
    atomicAdd(&y4[c * 4 + 2], nrm * x_car[r * 3 + 2]);
}

__global__ void k_fin(int nt, int nc,
                      const float* __restrict__ dis_t, const float* __restrict__ sumdis,
                      float* __restrict__ s_t,
                      const float* __restrict__ dis_c, const float* __restrict__ x_car,
                      float* __restrict__ y4) {
    int i = blockIdx.x * blockDim.x + threadIdx.x;
    if (i < nt) {
        float d = dis_t[i];
        s_t[i] = d * sumdis[i] + d * d;
    }
    if (i < nc) {
        float d2 = dis_c[i] * dis_c[i];
        y4[i * 4 + 0] += d2 * x_car[i * 3 + 0];
        y4[i * 4 + 1] += d2 * x_car[i * 3 + 1];
        y4[i * 4 + 2] += d2 * x_car[i * 3 + 2];
        y4[i * 4 + 3] = 1.0f;
    }
}

// ============ launch ============

extern "C" void kernel_launch(void* const* d_in, const int* in_sizes, int n_in,
                              void* d_out, int out_size, void* d_ws, size_t ws_size,
                              hipStream_t stream) {
    const float* x_car  = (const float*)d_in[0];
    const int*   ei_t   = (const int*)d_in[1];
    const int*   ei_c   = (const int*)d_in[2];
    const float* ew_c   = (const float*)d_in[3];
    const int*   src    = (const int*)d_in[4];
    const int*   dst    = (const int*)d_in[5];
    const float* W_t    = (const float*)d_in[7];
    const float* b_t    = (const float*)d_in[8];
    const float* W_c    = (const float*)d_in[9];
    const float* b_c    = (const float*)d_in[10];
    const float* W_lin  = (const float*)d_in[11];
    const float* b_lin  = (const float*)d_in[12];
    float* out = (float*)d_out;

    const int NC = in_sizes[0] / 3;   // 100000
    const int E_ = in_sizes[1] / 2;   // 1600000
    const int P_ = in_sizes[4];       // 200000

    const int* trow = ei_t;  const int* tcol = ei_t + E_;
    const int* crow = ei_c;  const int* ccol = ei_c + E_;

    char* ws = (char*)d_ws;
    int gP = (P_ + BLK - 1) / BLK;
    int chunk = (E_ + PB - 1) / PB;

    if (ws_size >= WS_NEED_NEW && chunk <= CHUNK_MAX && NB * NPB >= N_TRUCK &&
        NB * NPB >= NC && NB * CAP >= E_ + 8192) {
        int*      curT  = (int*)(ws + 0);
        int*      curC  = (int*)(ws + 1024);
        float*    G     = (float*)(ws + 2048);
        float*    dis_t = (float*)(ws + 4096);
        float*    dis_c = (float*)(ws + 404096);
        float*    s_t   = (float*)(ws + 804096);
        float*    y4    = (float*)(ws + 1204096);
        float4*   xs4   = (float4*)(ws + 2804096);
        unsigned* pT    = (unsigned*)(ws + 4404096);
        u64*      pC8   = (u64*)(ws + 12792704);

        hipMemsetAsync(ws, 0, 2048, stream);   // cursors
        k_place<<<PB + 1, BLK_P, 0, stream>>>(trow, tcol, crow, ccol, ew_c, E_,
                                              curT, curC, pT, pC8,
                                              W_t, b_t, W_c, b_c, W_lin, G);
        k_deg2<<<2 * NB, BLK_P, 0, stream>>>(pT, pC8, curT, curC, x_car,
                                             dis_t, dis_c, xs4, N_TRUCK, NC);
        k_agg<<<2 * NB, BLK_P, 0, stream>>>(pT, pC8, curT, curC, dis_t, dis_c,
                                            xs4, s_t, (float4*)y4, N_TRUCK, NC);
        k_pairs<<<gP, BLK, 0, stream>>>(src, dst, P_, s_t, (const float4*)y4, G, b_lin, out);
    } else {
        // fallback: round-1 proven global-atomic path (~4 MB ws)
        int*   cnt_t  = (int*)(ws + 0);
        float* sumdis = (float*)(ws + 400000);
        float* degw_c = (float*)(ws + 800000);
        float* y4     = (float*)(ws + 1200000);
        float* dis_t  = (float*)(ws + 2800000);
        float* dis_c  = (float*)(ws + 3200000);
        float* s_t    = (float*)(ws + 3600000);
        float* G      = (float*)(ws + 4000000);

        hipMemsetAsync(ws, 0, 2800000, stream);
        int gE = (E_ + BLK - 1) / BLK;
        int gN = ((N_TRUCK > NC ? N_TRUCK : NC) + BLK - 1) / BLK;
        k_deg<<<gE, BLK, 0, stream>>>(tcol, ccol, ew_c, E_, cnt_t, degw_c);
        k_dis<<<gN, BLK, 0, stream>>>(cnt_t, degw_c, dis_t, dis_c, N_TRUCK, NC);
        k_scat<<<gE, BLK, 0, stream>>>(trow, tcol, crow, ccol, ew_c, E_,
                                       dis_t, dis_c, x_car, sumdis, y4);
        k_fin<<<gN, BLK, 0, stream>>>(N_TRUCK, NC, dis_t, sumdis, s_t, dis_c, x_car, y4);
        k_G<<<1, 64, 0, stream>>>(W_t, b_t, W_c, b_c, W_lin, G);
        k_pairs<<<gP, BLK, 0, stream>>>(src, dst, P_, s_t, (const float4*)y4, G, b_lin, out);
    }
}